// Round 22
// baseline (156.153 us; speedup 1.0000x reference)
//
#include <hip/hip_runtime.h>
#include <hip/hip_bf16.h>
#include <math.h>

typedef unsigned short u16;
typedef __attribute__((ext_vector_type(4))) unsigned short u16x4;
typedef __attribute__((ext_vector_type(8))) unsigned short u16x8;
typedef __attribute__((ext_vector_type(8))) short s16x8;
typedef __attribute__((ext_vector_type(4))) float f32x4;
typedef __attribute__((ext_vector_type(16))) float f32x16;
typedef __attribute__((ext_vector_type(4))) unsigned int u32x4;

#define BB 4
#define SS 2048
#define DD 512
#define HH 8
#define DKK 64
#define FFF 2048

// Q pre-scale: 1/sqrt(DK) * log2(e), so softmax uses exp2 directly.
#define QSCALE 0.18033688011112042f

#define GLP(p) ((const __attribute__((address_space(1))) void*)(p))
#define LDP(p) ((__attribute__((address_space(3))) void*)(p))

__device__ __forceinline__ float bf2f(u16 u){
  union { unsigned int i; float f; } x; x.i = ((unsigned int)u)<<16; return x.f;
}
__device__ __forceinline__ u16 f2bf(float f){
  union { float fl; unsigned int i; } x; x.fl = f;
  unsigned int r = x.i + 0x7fffu + ((x.i>>16)&1u);   // RNE
  return (u16)(r>>16);
}
__device__ __forceinline__ unsigned cvt_pk_bf16(float a, float b){
  unsigned d;
  asm volatile("v_cvt_pk_bf16_f32 %0, %1, %2" : "=v"(d) : "v"(a), "v"(b));
  return d;
}
// v_permlane32_swap_b32: a' = {a[0:31], b[0:31]}, b' = {a[32:63], b[32:63]}
__device__ __forceinline__ void pl32swap(unsigned &a, unsigned &b){
  asm volatile("v_permlane32_swap_b32 %0, %1" : "+v"(a), "+v"(b));
}

// ---------------- LayerNorm (fp32 in): one wave per row of 512 -> bf16 out ----------------
__global__ __launch_bounds__(256) void ln_k(const float* __restrict__ x, const float* __restrict__ g,
                     const float* __restrict__ b, u16* __restrict__ o){
  int row = blockIdx.x*4 + (threadIdx.x>>6);
  int lane = threadIdx.x & 63;
  const float* xr = x + (size_t)row*DD + lane*8;
  float4 v0 = *(const float4*)xr;
  float4 v1 = *(const float4*)(xr+4);
  float f[8] = {v0.x,v0.y,v0.z,v0.w,v1.x,v1.y,v1.z,v1.w};
  float s=0.f, s2=0.f;
#pragma unroll
  for (int i=0;i<8;i++){ s+=f[i]; s2+=f[i]*f[i]; }
#pragma unroll
  for (int off=1; off<64; off<<=1){ s += __shfl_xor(s, off); s2 += __shfl_xor(s2, off); }
  float mu = s * (1.f/DD);
  float var = s2 * (1.f/DD) - mu*mu;
  float rs = rsqrtf(var + 1e-6f);
  float4 g0 = *(const float4*)(g + lane*8);
  float4 g1 = *(const float4*)(g + lane*8 + 4);
  float4 b0 = *(const float4*)(b + lane*8);
  float4 b1 = *(const float4*)(b + lane*8 + 4);
  float gg[8] = {g0.x,g0.y,g0.z,g0.w,g1.x,g1.y,g1.z,g1.w};
  float bb[8] = {b0.x,b0.y,b0.z,b0.w,b1.x,b1.y,b1.z,b1.w};
  u16x8 ov;
#pragma unroll
  for (int i=0;i<8;i++) ov[i] = f2bf((f[i]-mu)*rs*gg[i] + bb[i]);
  *(u16x8*)(o + (size_t)row*DD + lane*8) = ov;
}

// ---------------- LayerNorm (bf16 in): for the bf16 residual stream x1 ----------------
__global__ __launch_bounds__(256) void lnb_k(const u16* __restrict__ x, const float* __restrict__ g,
                     const float* __restrict__ b, u16* __restrict__ o){
  int row = blockIdx.x*4 + (threadIdx.x>>6);
  int lane = threadIdx.x & 63;
  u16x8 v = *(const u16x8*)(x + (size_t)row*DD + lane*8);
  float f[8]; float s=0.f, s2=0.f;
#pragma unroll
  for (int i=0;i<8;i++){ f[i]=bf2f(v[i]); s+=f[i]; s2+=f[i]*f[i]; }
#pragma unroll
  for (int off=1; off<64; off<<=1){ s += __shfl_xor(s, off); s2 += __shfl_xor(s2, off); }
  float mu = s * (1.f/DD);
  float var = s2 * (1.f/DD) - mu*mu;
  float rs = rsqrtf(var + 1e-6f);
  float4 g0 = *(const float4*)(g + lane*8);
  float4 g1 = *(const float4*)(g + lane*8 + 4);
  float4 b0 = *(const float4*)(b + lane*8);
  float4 b1 = *(const float4*)(b + lane*8 + 4);
  float gg[8] = {g0.x,g0.y,g0.z,g0.w,g1.x,g1.y,g1.z,g1.w};
  float bb[8] = {b0.x,b0.y,b0.z,b0.w,b1.x,b1.y,b1.z,b1.w};
  u16x8 ov;
#pragma unroll
  for (int i=0;i<8;i++) ov[i] = f2bf((f[i]-mu)*rs*gg[i] + bb[i]);
  *(u16x8*)(o + (size_t)row*DD + lane*8) = ov;
}

// ---------------- fused weight prep: all 6 transposes (fp32 [R][C] -> bf16 [C][R]) ----------------
__global__ __launch_bounds__(256) void wprep_k(
    const float* __restrict__ Wq, const float* __restrict__ Wk,
    const float* __restrict__ Wv, const float* __restrict__ Wo,
    const float* __restrict__ W1, const float* __restrict__ W2,
    u16* __restrict__ wtq, u16* __restrict__ wtk, u16* __restrict__ wtv,
    u16* __restrict__ wto, u16* __restrict__ wt1, u16* __restrict__ wt2){
  __shared__ u16 tile[64][72];
  int id = blockIdx.x;
  const float* src; u16* dst; int R, C, bx, by;
  if (id < 256){
    int m = id >> 6, s = id & 63;
    src = (m==0)?Wq:(m==1)?Wk:(m==2)?Wv:Wo;
    dst = (m==0)?wtq:(m==1)?wtk:(m==2)?wtv:wto;
    R = 512; C = 512; bx = s&7; by = s>>3;
  } else if (id < 512){
    int s = id - 256; src = W1; dst = wt1; R = 512; C = 2048; bx = s&31; by = s>>5;
  } else {
    int s = id - 512; src = W2; dst = wt2; R = 2048; C = 512; bx = s&7; by = s>>3;
  }
  int r0 = by*64, c0 = bx*64;
  int t = threadIdx.x;
#pragma unroll
  for (int i=0;i<2;i++){
    int u = t + 256*i;
    int r = u>>3, cb = (u&7)*8;
    const float* sp = src + (size_t)(r0+r)*C + c0 + cb;
    float4 v0 = *(const float4*)sp;
    float4 v1 = *(const float4*)(sp+4);
    float f[8] = {v0.x,v0.y,v0.z,v0.w,v1.x,v1.y,v1.z,v1.w};
#pragma unroll
    for (int j=0;j<8;j++) tile[r][cb+j] = f2bf(f[j]);
  }
  __syncthreads();
#pragma unroll
  for (int i=0;i<2;i++){
    int u = t + 256*i;
    int c = u>>3, rb = (u&7)*8;
    u16x8 ov;
#pragma unroll
    for (int j=0;j<8;j++) ov[j] = tile[rb+j][c];
    *(u16x8*)(dst + (size_t)(c0+c)*R + r0 + rb) = ov;
  }
}

// bijective XCD-chunk swizzle of the flattened block id (all grids here %8==0)
__device__ __forceinline__ void xcd_swz(unsigned& bx, unsigned& by, unsigned& bz){
  unsigned nx = gridDim.x, ny = gridDim.y;
  unsigned nwg = nx*ny*gridDim.z;
  unsigned f = blockIdx.x + nx*(blockIdx.y + ny*blockIdx.z);
  unsigned fs = (f & 7)*(nwg >> 3) + (f >> 3);
  bx = fs % nx; unsigned rem = fs / nx;
  by = rem % ny; bz = rem / ny;
}

// ---------------- GEMM: C[M,N] = A[M,K] * Bt[N,K]^T (+bias/+res/+gelu) ----------------
// BM x 128 tile, BK=64, NW waves, double-buffered with COUNTED-vmcnt barriers (T4):
// per kstep: GSTAGE(next) -> s_waitcnt vmcnt(L) (drains THIS tile's loads, leaves
// next-tile loads in flight ACROSS the barrier) -> s_barrier -> compute -> s_barrier.
// Validated r21: -2.6us vs __syncthreads' full vmcnt(0) drain.
// Wave decomposition: NFR = BM/(8*NW); NWC = 128/(16*NFR).
// Staging: global_load_lds width=16, pre-swizzled source (byte ^= ((row&7)<<4)).
// EPI 0: QKV (z==2: V transposed to Vt via 8B stores). EPI 1: +bias+res(f32)->bf16.
// EPI 2: +bias+gelu->bf16. EPI 3: +bias+res(bf16)->f32.
template<int EPI, int BM, int NW>
__global__ __launch_bounds__(NW*64) void gemm_bt(const u16* __restrict__ A, const u16* __restrict__ Bt,
    void* __restrict__ Cv, const float* __restrict__ bias, const void* __restrict__ resv,
    int M, int N, int K, long zB, long zC){
  constexpr int NFR = BM/(8*NW);
  constexpr int NWC = 128/(16*NFR);
  constexpr int LW  = (NW==8) ? ((BM==128)?4:3) : ((BM==128)?8:6);  // loads/wave/GSTAGE
  unsigned bxs, bys, bzs;
  xcd_swz(bxs, bys, bzs);
  Bt += (size_t)bzs * zB;
  __shared__ u16 la[2][BM*64];
  __shared__ u16 lb[2][128*64];
  int t = threadIdx.x, lane = t&63, w = t>>6;
  int wr = w / NWC;
  int wc = w % NWC;
  int m0 = bys*BM, n0 = bxs*128;
  int r = lane&15, g = lane>>4;
  int cbx = ((lane&7) ^ (lane>>3))*16;   // pre-swizzled source byte offset
  int lrow = lane>>3;
  f32x4 acc[4][NFR];
#pragma unroll
  for (int m=0;m<4;m++)
#pragma unroll
    for (int n=0;n<NFR;n++) acc[m][n] = (f32x4)0.f;

#define GSTAGE(buf, k0) do { \
    if (NW==8){ \
      _Pragma("unroll") \
      for (int i_=0;i_<2;i_++){ \
        int br_ = 8*(w + 8*i_); \
        int row_ = br_ + lrow; \
        if (BM==128 || i_==0) \
          __builtin_amdgcn_global_load_lds( \
            GLP((const char*)(A + (size_t)(m0+row_)*K + (k0)) + cbx), \
            LDP((char*)la[buf] + br_*128), 16, 0, 0); \
        __builtin_amdgcn_global_load_lds( \
          GLP((const char*)(Bt + (size_t)(n0+row_)*K + (k0)) + cbx), \
          LDP((char*)lb[buf] + br_*128), 16, 0, 0); \
      } \
    } else { \
      _Pragma("unroll") \
      for (int i_=0;i_<4;i_++){ \
        int br_ = 8*w + 32*i_; \
        int row_ = br_ + lrow; \
        if (BM==128 || i_<2) \
          __builtin_amdgcn_global_load_lds( \
            GLP((const char*)(A + (size_t)(m0+row_)*K + (k0)) + cbx), \
            LDP((char*)la[buf] + br_*128), 16, 0, 0); \
        __builtin_amdgcn_global_load_lds( \
          GLP((const char*)(Bt + (size_t)(n0+row_)*K + (k0)) + cbx), \
          LDP((char*)lb[buf] + br_*128), 16, 0, 0); \
      } \
    } } while(0)

  GSTAGE(0, 0);
  int nk = K >> 6;
  for (int ki=0; ki<nk; ki++){
    int cur = ki & 1;
    if (ki+1 < nk){
      GSTAGE(cur^1, (ki+1)*64);
      asm volatile("s_waitcnt vmcnt(%0)" :: "n"(LW) : "memory");
    } else {
      asm volatile("s_waitcnt vmcnt(0)" ::: "memory");
    }
    __builtin_amdgcn_s_barrier();       // all waves' tile-ki loads now in LDS
    asm volatile("" ::: "memory");
    const u16* lac = la[cur];
    const u16* lbc = lb[cur];
    s16x8 bfr[NFR][2];
#pragma unroll
    for (int n=0;n<NFR;n++)
#pragma unroll
      for (int kk=0;kk<2;kk++){
        int row = wc*(16*NFR) + n*16 + r;
        int cb = kk*64 + g*16;
        bfr[n][kk] = *(const s16x8*)((const char*)lbc + row*128 + (cb ^ ((row&7)<<4)));
      }
#pragma unroll
    for (int m=0;m<4;m++){
      int row = wr*64 + m*16 + r;
      s16x8 a0 = *(const s16x8*)((const char*)lac + row*128 + ((g*16)      ^ ((row&7)<<4)));
      s16x8 a1 = *(const s16x8*)((const char*)lac + row*128 + ((64 + g*16) ^ ((row&7)<<4)));
#pragma unroll
      for (int n=0;n<NFR;n++){
        acc[m][n] = __builtin_amdgcn_mfma_f32_16x16x32_bf16(a0, bfr[n][0], acc[m][n], 0,0,0);
        acc[m][n] = __builtin_amdgcn_mfma_f32_16x16x32_bf16(a1, bfr[n][1], acc[m][n], 0,0,0);
      }
    }
    asm volatile("" ::: "memory");
    __builtin_amdgcn_s_barrier();       // reads of tile ki complete before overwrite
  }
#undef GSTAGE
  // epilogue: C[i][j], i = 4*(lane>>4)+reg, j = lane&15  (m89-verified layout)
  if (EPI==0 && bzs==2){
    // V: write transposed into Vt[b][h][dk][s]; 4 regs = 4 consecutive s -> 8B store
    u16* vt = (u16*)resv;
#pragma unroll
    for (int m=0;m<4;m++)
#pragma unroll
      for (int n=0;n<NFR;n++){
        int col = n0 + wc*(16*NFR) + n*16 + r;
        int row0 = m0 + wr*64 + m*16 + g*4;
        int bq = row0 >> 11, s0 = row0 & (SS-1);
        int hh = col >> 6, dk = col & 63;
        u16x4 pk;
#pragma unroll
        for (int reg=0; reg<4; reg++) pk[reg] = f2bf(acc[m][n][reg]);
        *(u16x4*)(vt + (((size_t)(bq*HH + hh)*DKK + dk)*SS + s0)) = pk;
      }
    return;
  }
  float scl = (EPI==0 && bzs==0) ? QSCALE : 1.f;
#pragma unroll
  for (int m=0;m<4;m++)
#pragma unroll
    for (int n=0;n<NFR;n++){
      int col = n0 + wc*(16*NFR) + n*16 + r;
#pragma unroll
      for (int reg=0; reg<4; reg++){
        int row = m0 + wr*64 + m*16 + g*4 + reg;
        float v = acc[m][n][reg];
        if (EPI==1){         // + bias + fp32 residual -> bf16 (x1 stream)
          v += bias[col] + ((const float*)resv)[(size_t)row*N + col];
          ((u16*)Cv)[(size_t)row*N + col] = f2bf(v);
        } else if (EPI==3){  // + bias + bf16 residual -> fp32 (final out)
          v += bias[col] + bf2f(((const u16*)resv)[(size_t)row*N + col]);
          ((float*)Cv)[(size_t)row*N + col] = v;
        } else if (EPI==2){
          v += bias[col];
          // gelu(v) ~= v * sigmoid(v*(a + b*v^2)), exp2 domain; max abs err ~3e-4
          float y = v*(2.30211416f + 0.10294904f*v*v);
          float sg = 1.f/(1.f + __builtin_amdgcn_exp2f(-y));
          ((u16*)Cv)[(size_t)row*N + col] = f2bf(v*sg);
        } else {
          ((u16*)Cv + (size_t)bzs*zC)[(size_t)row*N + col] = f2bf(v*scl);
        }
      }
    }
}

// ---------------- flash attention, 32x32 MFMA, IN-BLOCK SPLIT-K=2 ----------------
// grid (S/128, H, B), 512 threads = 8 waves: wave w -> q-subtile wq=w&3, k-half kh=w>>2.
// Each wave: 16 k-tiles of 64 over its half, 2-slot LDS ring per half (64KB, 2 blocks/CU
// -> 4 waves/SIMD). COUNTED-vmcnt barriers (T4, r21-proven on GEMM): ASTAGE(next) ->
// vmcnt(4) (retire current tile's 4 loads/wave, prefetch stays in flight across the
// barrier) -> s_barrier -> compute -> s_barrier. Replaces __syncthreads' vmcnt(0) drain.
// Combine IN LDS; O=(O0+O1)/(l0+l1) -- max-free softmax (r6).
// QK^T swapped per 32-k block: mfma_32x32x16(K, Q) -> lane holds P^T[kk][q=lane&31].
// P-routing via cvt_pk + v_permlane32_swap. LDS swizzle: slot = cb16 ^ rsw,
// rsw = (l31&7)^((l31>>3)&3). |s| < ~8 so exp2 needs no max subtraction.
__global__ __launch_bounds__(512,4) void attn_k(const u16* __restrict__ Q, const u16* __restrict__ Kb,
    const u16* __restrict__ Vt, u16* __restrict__ ctx){
  unsigned bxs, bys, bzs;
  xcd_swz(bxs, bys, bzs);
  int q0 = bxs*128; int h = bys; int b = bzs;
  int t = threadIdx.x, lane = t&63, w = t>>6;
  int wq = w&3, kh = w>>2;
  int l31 = lane&31, lh = lane>>5;
  int kbase = kh*(SS/2);
  __shared__ u16 kt[2][2][64*64];     // [kh][slot][k][d] swizzled content
  __shared__ u16 vt[2][2][64*64];     // [kh][slot][d][k] swizzled content
  // Q B-frags: lane holds Q[q = q0+wq*32+l31][d = 16*dblk + 8*lh + j]
  const u16* qbase = Q + ((size_t)(b*SS) + q0 + wq*32 + l31)*DD + h*DKK + lh*8;
  s16x8 qf[4];
#pragma unroll
  for (int dblk=0;dblk<4;dblk++) qf[dblk] = *(const s16x8*)(qbase + 16*dblk);
  float l_ = 0.f;
  f32x16 cacc[2];
  cacc[0] = (f32x16)0.f; cacc[1] = (f32x16)0.f;
  int cbx = ((lane&7) ^ (lane>>3) ^ wq)*16;  // pre-swizzled source byte offset
  int lrow = lane>>3;
  int rsw = (l31&7) ^ ((l31>>3)&3);          // read-swizzle, 32-row-block invariant

#define ASTAGE(slot, kk0) do { \
    _Pragma("unroll") \
    for (int i_=0;i_<2;i_++){ \
      int br_ = 8*(wq + 4*i_); \
      int row_ = br_ + lrow; \
      __builtin_amdgcn_global_load_lds( \
        GLP((const char*)(Kb + ((size_t)(b*SS) + (kk0) + row_)*DD + h*DKK) + cbx), \
        LDP((char*)kt[kh][slot] + br_*128), 16, 0, 0); \
      __builtin_amdgcn_global_load_lds( \
        GLP((const char*)(Vt + ((size_t)(b*HH+h)*DKK + row_)*SS + (kk0)) + cbx), \
        LDP((char*)vt[kh][slot] + br_*128), 16, 0, 0); \
    } } while(0)

  // swizzled LDS b128 read: row = blk32*32 + l31, cb16 = 16B-chunk index
  auto ldk = [&](const u16* base, int blk32, int cb16)->s16x8 {
    int row = blk32*32 + l31;
    int slot = cb16 ^ rsw;
    return *(const s16x8*)((const char*)base + row*128 + slot*16);
  };

  auto tile_compute = [&](const u16* ktc, const u16* vtc){
    // QK^T: two 32-kk blocks, each accumulating over d=64 (4 MFMAs of K=16)
    f32x16 sc[2];
    sc[0] = (f32x16)0.f; sc[1] = (f32x16)0.f;
    __builtin_amdgcn_s_setprio(1);
#pragma unroll
    for (int kkb=0;kkb<2;kkb++){
#pragma unroll
      for (int dblk=0;dblk<4;dblk++){
        s16x8 kf = ldk(ktc, kkb, 2*dblk + lh);
        sc[kkb] = __builtin_amdgcn_mfma_f32_32x32x16_bf16(kf, qf[dblk], sc[kkb], 0,0,0);
      }
    }
    __builtin_amdgcn_s_setprio(0);
    // unnormalized softmax: p = exp2(s); lane sums its 32 kk's for q=l31,
    // partner half (lane^32) has the other 32 -> one shfl_xor(32)
    float ps = 0.f;
#pragma unroll
    for (int kkb=0;kkb<2;kkb++)
#pragma unroll
      for (int i=0;i<16;i++){
        float p = __builtin_amdgcn_exp2f(sc[kkb][i]);
        sc[kkb][i] = p;
        ps += p;
      }
    ps += __shfl_xor(ps, 32);
    l_ += ps;
    // pack to bf16 pairs: c[kkb][i] = (reg 2i, reg 2i+1)
    unsigned c0[8], c1[8];
#pragma unroll
    for (int i=0;i<8;i++){
      c0[i] = cvt_pk_bf16(sc[0][2*i], sc[0][2*i+1]);
      c1[i] = cvt_pk_bf16(sc[1][2*i], sc[1][2*i+1]);
    }
    // route to PV A-frags via permlane32_swap: frag t covers k=16t..16t+15;
    // (w0,w2)=swap(c[4s],c[4s+2]); (w1,w3)=swap(c[4s+1],c[4s+3]); s=t&1, kkb=t>>1
    s16x8 pa[4];
#pragma unroll
    for (int t_=0;t_<4;t_++){
      unsigned* cc = (t_>>1) ? c1 : c0;
      int s = (t_&1)*4;
      unsigned w0 = cc[s+0], w2 = cc[s+2];
      unsigned w1 = cc[s+1], w3 = cc[s+3];
      pl32swap(w0, w2);
      pl32swap(w1, w3);
      u32x4 fw; fw[0]=w0; fw[1]=w1; fw[2]=w2; fw[3]=w3;
      pa[t_] = __builtin_bit_cast(s16x8, fw);
    }
    // PV: O[q][d] two 32-d blocks; B = V[k][d] read k-contiguous from Vt[d][k]
    __builtin_amdgcn_s_setprio(1);
#pragma unroll
    for (int db=0;db<2;db++){
#pragma unroll
      for (int t_=0;t_<4;t_++){
        s16x8 vf = ldk(vtc, db, 2*t_ + lh);
        cacc[db] = __builtin_amdgcn_mfma_f32_32x32x16_bf16(pa[t_], vf, cacc[db], 0,0,0);
      }
    }
    __builtin_amdgcn_s_setprio(0);
  };

  ASTAGE(0, kbase);
  for (int ti=0; ti<16; ti++){
    int cur = ti & 1;
    if (ti+1 < 16){
      ASTAGE(cur^1, kbase + (ti+1)*64);
      asm volatile("s_waitcnt vmcnt(4)" ::: "memory");   // retire tile-ti's 4 loads
    } else {
      asm volatile("s_waitcnt vmcnt(0)" ::: "memory");
    }
    __builtin_amdgcn_s_barrier();       // all waves' tile-ti loads now in LDS
    asm volatile("" ::: "memory");
    tile_compute(kt[kh][cur], vt[kh][cur]);
    asm volatile("" ::: "memory");
    __builtin_amdgcn_s_barrier();       // reads of tile ti complete before overwrite
  }
#undef ASTAGE
  // ---- in-LDS split-K combine (kt/vt space is free after the final barrier) ----
  // kh=1 waves publish unnormalized O (f32) + l; kh=0 waves sum, normalize, write ctx.
  float* ob = (float*)kt;           // 4 subtiles x 32q x 64d f32 = 32KB (fits kt exactly)
  float* lf = (float*)vt;           // 128 f32
  if (kh == 1){
#pragma unroll
    for (int db=0;db<2;db++)
#pragma unroll
      for (int reg=0;reg<16;reg++){
        int ql = (reg&3) + 8*(reg>>2) + 4*lh;
        ob[wq*2048 + ql*64 + db*32 + l31] = cacc[db][reg];
      }
    if (lh == 0) lf[wq*32 + l31] = l_;
  }
  __syncthreads();
  if (kh == 0){
    float ltot = l_ + lf[wq*32 + l31];
#pragma unroll
    for (int db=0;db<2;db++)
#pragma unroll
      for (int reg=0;reg<16;reg++){
        int ql = (reg&3) + 8*(reg>>2) + 4*lh;
        cacc[db][reg] += ob[wq*2048 + ql*64 + db*32 + l31];
      }
    size_t pb = (size_t)(b*SS) + q0 + wq*32;
    size_t co = (size_t)h*DKK + l31;
#pragma unroll
    for (int reg=0;reg<16;reg++){
      int qrow = (reg&3) + 8*(reg>>2) + 4*lh;
      float linv = 1.f/__shfl(ltot, qrow);
      ctx[(pb + qrow)*DD + co]      = f2bf(cacc[0][reg]*linv);
      ctx[(pb + qrow)*DD + co + 32] = f2bf(cacc[1][reg]*linv);
    }
  }
}

extern "C" void kernel_launch(void* const* d_in, const int* in_sizes, int n_in,
                              void* d_out, int out_size, void* d_ws, size_t ws_size,
                              hipStream_t stream){
  const float* x   = (const float*)d_in[0];
  const float* Wq  = (const float*)d_in[1];
  const float* Wk  = (const float*)d_in[2];
  const float* Wv  = (const float*)d_in[3];
  const float* Wo  = (const float*)d_in[4];
  const float* bo  = (const float*)d_in[5];
  const float* g1  = (const float*)d_in[6];
  const float* b1  = (const float*)d_in[7];
  const float* g2  = (const float*)d_in[8];
  const float* b2  = (const float*)d_in[9];
  const float* W1  = (const float*)d_in[10];
  const float* bf1 = (const float*)d_in[11];
  const float* W2  = (const float*)d_in[12];
  const float* bf2 = (const float*)d_in[13];
  float* out = (float*)d_out;

  char* p = (char*)d_ws;
  u16* wtq = (u16*)p;                p += (size_t)512*512*2;
  u16* wtk = (u16*)p;                p += (size_t)512*512*2;
  u16* wtv = (u16*)p;                p += (size_t)512*512*2;
  u16* wto = (u16*)p;                p += (size_t)512*512*2;
  u16* wt1 = (u16*)p;                p += (size_t)2048*512*2;
  u16* wt2 = (u16*)p;                p += (size_t)512*2048*2;
  u16* xn1 = (u16*)p;                p += (size_t)8192*512*2;  // reused: ctx, xn2
  u16* Qb  = (u16*)p;                p += (size_t)8192*512*2;  // hb overlay starts here (32MB)
  u16* Kb  = (u16*)p;                p += (size_t)8192*512*2;
  u16* Vtb = (u16*)p;                p += (size_t)8192*512*2;  // V written transposed by QKV GEMM
  /* hb spacer */                    p += (size_t)8192*512*2;  // 4th 8MB of the hb overlay --
                                                               // keeps FFN1's 32MB write off x1b
  u16* x1b = (u16*)p;                p += (size_t)8192*512*2;  // bf16 residual stream
  u16* hb  = Qb;                     // 8192x2048 bf16 = 32MB overlay: Qb+Kb+Vtb+spacer

  dim3 blk(256);
  // all weight transposes -> Wt[N][K] bf16, one dispatch
  wprep_k<<<dim3(768), blk, 0, stream>>>(Wq, Wk, Wv, Wo, W1, W2,
                                         wtq, wtk, wtv, wto, wt1, wt2);
  // LN1: fp32 x -> bf16 xn1
  ln_k<<<dim3(2048), blk, 0, stream>>>(x, g1, b1, xn1);
  // Q,K,V = xn1 @ W{q,k,v}; z==0 Q (*QSCALE), z==1 K, z==2 V -> Vt (transposed epilogue)
  gemm_bt<0,128,8><<<dim3(4,64,3), dim3(512), 0, stream>>>(xn1, wtq, Qb, nullptr, Vtb,
                                                   8192,512,512, (long)512*512, (long)8192*512);
  // attention (in-block split-K) -> normalized ctx (reuses xn1)
  attn_k<<<dim3(16,8,4), dim3(512), 0, stream>>>(Qb, Kb, Vtb, xn1);
  // x1 = x + ctx @ Wo + bo   (bf16 out; res = fp32 x)
  gemm_bt<1,64,8><<<dim3(4,128,1), dim3(512), 0, stream>>>(xn1, wto, x1b, bo, x, 8192,512,512, 0,0);
  // LN2: bf16 x1 -> bf16 xn2 (reuses xn1)
  lnb_k<<<dim3(2048), blk, 0, stream>>>(x1b, g2, b2, xn1);
  // h = gelu(xn2 @ W1 + bf1)  (bf16 out)
  gemm_bt<2,128,8><<<dim3(16,64,1), dim3(512), 0, stream>>>(xn1, wt1, hb, bf1, nullptr, 8192,2048,512, 0,0);
  // out = x1 + h @ W2 + bf2  (fp32 out; res = bf16 x1)
  gemm_bt<3,64,8><<<dim3(4,128,1), dim3(512), 0, stream>>>(hb, wt2, out, bf2, x1b, 8192,512,2048, 0,0);
}

// Round 23
// 152.527 us; speedup vs baseline: 1.0238x; 1.0238x over previous
//
#include <hip/hip_runtime.h>
#include <hip/hip_bf16.h>
#include <math.h>

typedef unsigned short u16;
typedef __attribute__((ext_vector_type(4))) unsigned short u16x4;
typedef __attribute__((ext_vector_type(8))) unsigned short u16x8;
typedef __attribute__((ext_vector_type(8))) short s16x8;
typedef __attribute__((ext_vector_type(4))) float f32x4;
typedef __attribute__((ext_vector_type(16))) float f32x16;
typedef __attribute__((ext_vector_type(4))) unsigned int u32x4;

#define BB 4
#define SS 2048
#define DD 512
#define HH 8
#define DKK 64
#define FFF 2048

// Q pre-scale: 1/sqrt(DK) * log2(e), so softmax uses exp2 directly.
#define QSCALE 0.18033688011112042f

#define GLP(p) ((const __attribute__((address_space(1))) void*)(p))
#define LDP(p) ((__attribute__((address_space(3))) void*)(p))

__device__ __forceinline__ float bf2f(u16 u){
  union { unsigned int i; float f; } x; x.i = ((unsigned int)u)<<16; return x.f;
}
__device__ __forceinline__ u16 f2bf(float f){
  union { float fl; unsigned int i; } x; x.fl = f;
  unsigned int r = x.i + 0x7fffu + ((x.i>>16)&1u);   // RNE
  return (u16)(r>>16);
}
__device__ __forceinline__ unsigned cvt_pk_bf16(float a, float b){
  unsigned d;
  asm volatile("v_cvt_pk_bf16_f32 %0, %1, %2" : "=v"(d) : "v"(a), "v"(b));
  return d;
}
// v_permlane32_swap_b32: a' = {a[0:31], b[0:31]}, b' = {a[32:63], b[32:63]}
__device__ __forceinline__ void pl32swap(unsigned &a, unsigned &b){
  asm volatile("v_permlane32_swap_b32 %0, %1" : "+v"(a), "+v"(b));
}

// ---------------- LayerNorm (bf16 in): for the bf16 residual stream x1 ----------------
__global__ __launch_bounds__(256) void lnb_k(const u16* __restrict__ x, const float* __restrict__ g,
                     const float* __restrict__ b, u16* __restrict__ o){
  int row = blockIdx.x*4 + (threadIdx.x>>6);
  int lane = threadIdx.x & 63;
  u16x8 v = *(const u16x8*)(x + (size_t)row*DD + lane*8);
  float f[8]; float s=0.f, s2=0.f;
#pragma unroll
  for (int i=0;i<8;i++){ f[i]=bf2f(v[i]); s+=f[i]; s2+=f[i]*f[i]; }
#pragma unroll
  for (int off=1; off<64; off<<=1){ s += __shfl_xor(s, off); s2 += __shfl_xor(s2, off); }
  float mu = s * (1.f/DD);
  float var = s2 * (1.f/DD) - mu*mu;
  float rs = rsqrtf(var + 1e-6f);
  float4 g0 = *(const float4*)(g + lane*8);
  float4 g1 = *(const float4*)(g + lane*8 + 4);
  float4 b0 = *(const float4*)(b + lane*8);
  float4 b1 = *(const float4*)(b + lane*8 + 4);
  float gg[8] = {g0.x,g0.y,g0.z,g0.w,g1.x,g1.y,g1.z,g1.w};
  float bb[8] = {b0.x,b0.y,b0.z,b0.w,b1.x,b1.y,b1.z,b1.w};
  u16x8 ov;
#pragma unroll
  for (int i=0;i<8;i++) ov[i] = f2bf((f[i]-mu)*rs*gg[i] + bb[i]);
  *(u16x8*)(o + (size_t)row*DD + lane*8) = ov;
}

// ---------------- fused prep: 6 weight transposes (blocks 0..767) + LN1 (blocks 768..2815) ----
// wprep and LN1 are INDEPENDENT (weights vs x) -- one dispatch lets them co-schedule
// across CUs instead of serializing as two launches.
__global__ __launch_bounds__(256) void prep_k(
    const float* __restrict__ Wq, const float* __restrict__ Wk,
    const float* __restrict__ Wv, const float* __restrict__ Wo,
    const float* __restrict__ W1, const float* __restrict__ W2,
    u16* __restrict__ wtq, u16* __restrict__ wtk, u16* __restrict__ wtv,
    u16* __restrict__ wto, u16* __restrict__ wt1, u16* __restrict__ wt2,
    const float* __restrict__ x, const float* __restrict__ g1,
    const float* __restrict__ b1, u16* __restrict__ xn){
  int id = blockIdx.x;
  if (id >= 768){
    // ---- LN1: fp32 x -> bf16 xn; one wave per row of 512 ----
    int row = (id-768)*4 + (threadIdx.x>>6);
    int lane = threadIdx.x & 63;
    const float* xr = x + (size_t)row*DD + lane*8;
    float4 v0 = *(const float4*)xr;
    float4 v1 = *(const float4*)(xr+4);
    float f[8] = {v0.x,v0.y,v0.z,v0.w,v1.x,v1.y,v1.z,v1.w};
    float s=0.f, s2=0.f;
#pragma unroll
    for (int i=0;i<8;i++){ s+=f[i]; s2+=f[i]*f[i]; }
#pragma unroll
    for (int off=1; off<64; off<<=1){ s += __shfl_xor(s, off); s2 += __shfl_xor(s2, off); }
    float mu = s * (1.f/DD);
    float var = s2 * (1.f/DD) - mu*mu;
    float rs = rsqrtf(var + 1e-6f);
    float4 g0 = *(const float4*)(g1 + lane*8);
    float4 g1v = *(const float4*)(g1 + lane*8 + 4);
    float4 b0 = *(const float4*)(b1 + lane*8);
    float4 b1v = *(const float4*)(b1 + lane*8 + 4);
    float gg[8] = {g0.x,g0.y,g0.z,g0.w,g1v.x,g1v.y,g1v.z,g1v.w};
    float bb[8] = {b0.x,b0.y,b0.z,b0.w,b1v.x,b1v.y,b1v.z,b1v.w};
    u16x8 ov;
#pragma unroll
    for (int i=0;i<8;i++) ov[i] = f2bf((f[i]-mu)*rs*gg[i] + bb[i]);
    *(u16x8*)(xn + (size_t)row*DD + lane*8) = ov;
    return;
  }
  // ---- weight transpose+cast: fp32 [R][C] -> bf16 [C][R] ----
  __shared__ u16 tile[64][72];
  const float* src; u16* dst; int R, C, bx, by;
  if (id < 256){
    int m = id >> 6, s = id & 63;
    src = (m==0)?Wq:(m==1)?Wk:(m==2)?Wv:Wo;
    dst = (m==0)?wtq:(m==1)?wtk:(m==2)?wtv:wto;
    R = 512; C = 512; bx = s&7; by = s>>3;
  } else if (id < 512){
    int s = id - 256; src = W1; dst = wt1; R = 512; C = 2048; bx = s&31; by = s>>5;
  } else {
    int s = id - 512; src = W2; dst = wt2; R = 2048; C = 512; bx = s&7; by = s>>3;
  }
  int r0 = by*64, c0 = bx*64;
  int t = threadIdx.x;
#pragma unroll
  for (int i=0;i<2;i++){
    int u = t + 256*i;
    int r = u>>3, cb = (u&7)*8;
    const float* sp = src + (size_t)(r0+r)*C + c0 + cb;
    float4 v0 = *(const float4*)sp;
    float4 v1 = *(const float4*)(sp+4);
    float f[8] = {v0.x,v0.y,v0.z,v0.w,v1.x,v1.y,v1.z,v1.w};
#pragma unroll
    for (int j=0;j<8;j++) tile[r][cb+j] = f2bf(f[j]);
  }
  __syncthreads();
#pragma unroll
  for (int i=0;i<2;i++){
    int u = t + 256*i;
    int c = u>>3, rb = (u&7)*8;
    u16x8 ov;
#pragma unroll
    for (int j=0;j<8;j++) ov[j] = tile[rb+j][c];
    *(u16x8*)(dst + (size_t)(c0+c)*R + r0 + rb) = ov;
  }
}

// bijective XCD-chunk swizzle of the flattened block id (all grids here %8==0)
__device__ __forceinline__ void xcd_swz(unsigned& bx, unsigned& by, unsigned& bz){
  unsigned nx = gridDim.x, ny = gridDim.y;
  unsigned nwg = nx*ny*gridDim.z;
  unsigned f = blockIdx.x + nx*(blockIdx.y + ny*blockIdx.z);
  unsigned fs = (f & 7)*(nwg >> 3) + (f >> 3);
  bx = fs % nx; unsigned rem = fs / nx;
  by = rem % ny; bz = rem / ny;
}

// ---------------- GEMM: C[M,N] = A[M,K] * Bt[N,K]^T (+bias/+res/+gelu) ----------------
// BM x 128 tile, BK=64, NW waves, double-buffered with COUNTED-vmcnt barriers (T4):
// per kstep: GSTAGE(next) -> s_waitcnt vmcnt(L) (drains THIS tile's loads, leaves
// next-tile loads in flight ACROSS the barrier) -> s_barrier -> compute -> s_barrier.
// Validated r21: -2.6us vs __syncthreads' full vmcnt(0) drain.
// Wave decomposition: NFR = BM/(8*NW); NWC = 128/(16*NFR).
// Staging: global_load_lds width=16, pre-swizzled source (byte ^= ((row&7)<<4)).
// EPI 0: QKV (z==2: V transposed to Vt via 8B stores). EPI 1: +bias+res(f32)->bf16.
// EPI 2: +bias+gelu->bf16. EPI 3: +bias+res(bf16)->f32.
template<int EPI, int BM, int NW>
__global__ __launch_bounds__(NW*64) void gemm_bt(const u16* __restrict__ A, const u16* __restrict__ Bt,
    void* __restrict__ Cv, const float* __restrict__ bias, const void* __restrict__ resv,
    int M, int N, int K, long zB, long zC){
  constexpr int NFR = BM/(8*NW);
  constexpr int NWC = 128/(16*NFR);
  constexpr int LW  = (NW==8) ? ((BM==128)?4:3) : ((BM==128)?8:6);  // loads/wave/GSTAGE
  unsigned bxs, bys, bzs;
  xcd_swz(bxs, bys, bzs);
  Bt += (size_t)bzs * zB;
  __shared__ u16 la[2][BM*64];
  __shared__ u16 lb[2][128*64];
  int t = threadIdx.x, lane = t&63, w = t>>6;
  int wr = w / NWC;
  int wc = w % NWC;
  int m0 = bys*BM, n0 = bxs*128;
  int r = lane&15, g = lane>>4;
  int cbx = ((lane&7) ^ (lane>>3))*16;   // pre-swizzled source byte offset
  int lrow = lane>>3;
  f32x4 acc[4][NFR];
#pragma unroll
  for (int m=0;m<4;m++)
#pragma unroll
    for (int n=0;n<NFR;n++) acc[m][n] = (f32x4)0.f;

#define GSTAGE(buf, k0) do { \
    if (NW==8){ \
      _Pragma("unroll") \
      for (int i_=0;i_<2;i_++){ \
        int br_ = 8*(w + 8*i_); \
        int row_ = br_ + lrow; \
        if (BM==128 || i_==0) \
          __builtin_amdgcn_global_load_lds( \
            GLP((const char*)(A + (size_t)(m0+row_)*K + (k0)) + cbx), \
            LDP((char*)la[buf] + br_*128), 16, 0, 0); \
        __builtin_amdgcn_global_load_lds( \
          GLP((const char*)(Bt + (size_t)(n0+row_)*K + (k0)) + cbx), \
          LDP((char*)lb[buf] + br_*128), 16, 0, 0); \
      } \
    } else { \
      _Pragma("unroll") \
      for (int i_=0;i_<4;i_++){ \
        int br_ = 8*w + 32*i_; \
        int row_ = br_ + lrow; \
        if (BM==128 || i_<2) \
          __builtin_amdgcn_global_load_lds( \
            GLP((const char*)(A + (size_t)(m0+row_)*K + (k0)) + cbx), \
            LDP((char*)la[buf] + br_*128), 16, 0, 0); \
        __builtin_amdgcn_global_load_lds( \
          GLP((const char*)(Bt + (size_t)(n0+row_)*K + (k0)) + cbx), \
          LDP((char*)lb[buf] + br_*128), 16, 0, 0); \
      } \
    } } while(0)

  GSTAGE(0, 0);
  int nk = K >> 6;
  for (int ki=0; ki<nk; ki++){
    int cur = ki & 1;
    if (ki+1 < nk){
      GSTAGE(cur^1, (ki+1)*64);
      asm volatile("s_waitcnt vmcnt(%0)" :: "n"(LW) : "memory");
    } else {
      asm volatile("s_waitcnt vmcnt(0)" ::: "memory");
    }
    __builtin_amdgcn_s_barrier();       // all waves' tile-ki loads now in LDS
    asm volatile("" ::: "memory");
    const u16* lac = la[cur];
    const u16* lbc = lb[cur];
    s16x8 bfr[NFR][2];
#pragma unroll
    for (int n=0;n<NFR;n++)
#pragma unroll
      for (int kk=0;kk<2;kk++){
        int row = wc*(16*NFR) + n*16 + r;
        int cb = kk*64 + g*16;
        bfr[n][kk] = *(const s16x8*)((const char*)lbc + row*128 + (cb ^ ((row&7)<<4)));
      }
#pragma unroll
    for (int m=0;m<4;m++){
      int row = wr*64 + m*16 + r;
      s16x8 a0 = *(const s16x8*)((const char*)lac + row*128 + ((g*16)      ^ ((row&7)<<4)));
      s16x8 a1 = *(const s16x8*)((const char*)lac + row*128 + ((64 + g*16) ^ ((row&7)<<4)));
#pragma unroll
      for (int n=0;n<NFR;n++){
        acc[m][n] = __builtin_amdgcn_mfma_f32_16x16x32_bf16(a0, bfr[n][0], acc[m][n], 0,0,0);
        acc[m][n] = __builtin_amdgcn_mfma_f32_16x16x32_bf16(a1, bfr[n][1], acc[m][n], 0,0,0);
      }
    }
    asm volatile("" ::: "memory");
    __builtin_amdgcn_s_barrier();       // reads of tile ki complete before overwrite
  }
#undef GSTAGE
  // epilogue: C[i][j], i = 4*(lane>>4)+reg, j = lane&15  (m89-verified layout)
  if (EPI==0 && bzs==2){
    // V: write transposed into Vt[b][h][dk][s]; 4 regs = 4 consecutive s -> 8B store
    u16* vt = (u16*)resv;
#pragma unroll
    for (int m=0;m<4;m++)
#pragma unroll
      for (int n=0;n<NFR;n++){
        int col = n0 + wc*(16*NFR) + n*16 + r;
        int row0 = m0 + wr*64 + m*16 + g*4;
        int bq = row0 >> 11, s0 = row0 & (SS-1);
        int hh = col >> 6, dk = col & 63;
        u16x4 pk;
#pragma unroll
        for (int reg=0; reg<4; reg++) pk[reg] = f2bf(acc[m][n][reg]);
        *(u16x4*)(vt + (((size_t)(bq*HH + hh)*DKK + dk)*SS + s0)) = pk;
      }
    return;
  }
  float scl = (EPI==0 && bzs==0) ? QSCALE : 1.f;
#pragma unroll
  for (int m=0;m<4;m++)
#pragma unroll
    for (int n=0;n<NFR;n++){
      int col = n0 + wc*(16*NFR) + n*16 + r;
#pragma unroll
      for (int reg=0; reg<4; reg++){
        int row = m0 + wr*64 + m*16 + g*4 + reg;
        float v = acc[m][n][reg];
        if (EPI==1){         // + bias + fp32 residual -> bf16 (x1 stream)
          v += bias[col] + ((const float*)resv)[(size_t)row*N + col];
          ((u16*)Cv)[(size_t)row*N + col] = f2bf(v);
        } else if (EPI==3){  // + bias + bf16 residual -> fp32 (final out)
          v += bias[col] + bf2f(((const u16*)resv)[(size_t)row*N + col]);
          ((float*)Cv)[(size_t)row*N + col] = v;
        } else if (EPI==2){
          v += bias[col];
          // gelu(v) ~= v * sigmoid(v*(a + b*v^2)), exp2 domain; max abs err ~3e-4
          float y = v*(2.30211416f + 0.10294904f*v*v);
          float sg = 1.f/(1.f + __builtin_amdgcn_exp2f(-y));
          ((u16*)Cv)[(size_t)row*N + col] = f2bf(v*sg);
        } else {
          ((u16*)Cv + (size_t)bzs*zC)[(size_t)row*N + col] = f2bf(v*scl);
        }
      }
    }
}

// ---------------- flash attention, 32x32 MFMA, IN-BLOCK SPLIT-K=2 ----------------
// grid (S/128, H, B), 512 threads = 8 waves: wave w -> q-subtile wq=w&3, k-half kh=w>>2.
// Each wave: 16 k-tiles of 64 over its half, 2-slot LDS ring per half (64KB, 2 blocks/CU
// -> 4 waves/SIMD). COUNTED-vmcnt barriers (T4): ASTAGE(next) -> vmcnt(4) -> s_barrier
// -> compute -> s_barrier. Combine IN LDS; O=(O0+O1)/(l0+l1) -- max-free softmax (r6).
// QK^T swapped per 32-k block: mfma_32x32x16(K, Q) -> lane holds P^T[kk][q=lane&31].
// P-routing via cvt_pk + v_permlane32_swap. LDS swizzle: slot = cb16 ^ rsw,
// rsw = (l31&7)^((l31>>3)&3). |s| < ~8 so exp2 needs no max subtraction.
__global__ __launch_bounds__(512,4) void attn_k(const u16* __restrict__ Q, const u16* __restrict__ Kb,
    const u16* __restrict__ Vt, u16* __restrict__ ctx){
  unsigned bxs, bys, bzs;
  xcd_swz(bxs, bys, bzs);
  int q0 = bxs*128; int h = bys; int b = bzs;
  int t = threadIdx.x, lane = t&63, w = t>>6;
  int wq = w&3, kh = w>>2;
  int l31 = lane&31, lh = lane>>5;
  int kbase = kh*(SS/2);
  __shared__ u16 kt[2][2][64*64];     // [kh][slot][k][d] swizzled content
  __shared__ u16 vt[2][2][64*64];     // [kh][slot][d][k] swizzled content
  // Q B-frags: lane holds Q[q = q0+wq*32+l31][d = 16*dblk + 8*lh + j]
  const u16* qbase = Q + ((size_t)(b*SS) + q0 + wq*32 + l31)*DD + h*DKK + lh*8;
  s16x8 qf[4];
#pragma unroll
  for (int dblk=0;dblk<4;dblk++) qf[dblk] = *(const s16x8*)(qbase + 16*dblk);
  float l_ = 0.f;
  f32x16 cacc[2];
  cacc[0] = (f32x16)0.f; cacc[1] = (f32x16)0.f;
  int cbx = ((lane&7) ^ (lane>>3) ^ wq)*16;  // pre-swizzled source byte offset
  int lrow = lane>>3;
  int rsw = (l31&7) ^ ((l31>>3)&3);          // read-swizzle, 32-row-block invariant

#define ASTAGE(slot, kk0) do { \
    _Pragma("unroll") \
    for (int i_=0;i_<2;i_++){ \
      int br_ = 8*(wq + 4*i_); \
      int row_ = br_ + lrow; \
      __builtin_amdgcn_global_load_lds( \
        GLP((const char*)(Kb + ((size_t)(b*SS) + (kk0) + row_)*DD + h*DKK) + cbx), \
        LDP((char*)kt[kh][slot] + br_*128), 16, 0, 0); \
      __builtin_amdgcn_global_load_lds( \
        GLP((const char*)(Vt + ((size_t)(b*HH+h)*DKK + row_)*SS + (kk0)) + cbx), \
        LDP((char*)vt[kh][slot] + br_*128), 16, 0, 0); \
    } } while(0)

  // swizzled LDS b128 read: row = blk32*32 + l31, cb16 = 16B-chunk index
  auto ldk = [&](const u16* base, int blk32, int cb16)->s16x8 {
    int row = blk32*32 + l31;
    int slot = cb16 ^ rsw;
    return *(const s16x8*)((const char*)base + row*128 + slot*16);
  };

  auto tile_compute = [&](const u16* ktc, const u16* vtc){
    // QK^T: two 32-kk blocks, each accumulating over d=64 (4 MFMAs of K=16)
    f32x16 sc[2];
    sc[0] = (f32x16)0.f; sc[1] = (f32x16)0.f;
    __builtin_amdgcn_s_setprio(1);
#pragma unroll
    for (int kkb=0;kkb<2;kkb++){
#pragma unroll
      for (int dblk=0;dblk<4;dblk++){
        s16x8 kf = ldk(ktc, kkb, 2*dblk + lh);
        sc[kkb] = __builtin_amdgcn_mfma_f32_32x32x16_bf16(kf, qf[dblk], sc[kkb], 0,0,0);
      }
    }
    __builtin_amdgcn_s_setprio(0);
    // unnormalized softmax: p = exp2(s); lane sums its 32 kk's for q=l31,
    // partner half (lane^32) has the other 32 -> one shfl_xor(32)
    float ps = 0.f;
#pragma unroll
    for (int kkb=0;kkb<2;kkb++)
#pragma unroll
      for (int i=0;i<16;i++){
        float p = __builtin_amdgcn_exp2f(sc[kkb][i]);
        sc[kkb][i] = p;
        ps += p;
      }
    ps += __shfl_xor(ps, 32);
    l_ += ps;
    // pack to bf16 pairs: c[kkb][i] = (reg 2i, reg 2i+1)
    unsigned c0[8], c1[8];
#pragma unroll
    for (int i=0;i<8;i++){
      c0[i] = cvt_pk_bf16(sc[0][2*i], sc[0][2*i+1]);
      c1[i] = cvt_pk_bf16(sc[1][2*i], sc[1][2*i+1]);
    }
    // route to PV A-frags via permlane32_swap: frag t covers k=16t..16t+15;
    // (w0,w2)=swap(c[4s],c[4s+2]); (w1,w3)=swap(c[4s+1],c[4s+3]); s=t&1, kkb=t>>1
    s16x8 pa[4];
#pragma unroll
    for (int t_=0;t_<4;t_++){
      unsigned* cc = (t_>>1) ? c1 : c0;
      int s = (t_&1)*4;
      unsigned w0 = cc[s+0], w2 = cc[s+2];
      unsigned w1 = cc[s+1], w3 = cc[s+3];
      pl32swap(w0, w2);
      pl32swap(w1, w3);
      u32x4 fw; fw[0]=w0; fw[1]=w1; fw[2]=w2; fw[3]=w3;
      pa[t_] = __builtin_bit_cast(s16x8, fw);
    }
    // PV: O[q][d] two 32-d blocks; B = V[k][d] read k-contiguous from Vt[d][k]
    __builtin_amdgcn_s_setprio(1);
#pragma unroll
    for (int db=0;db<2;db++){
#pragma unroll
      for (int t_=0;t_<4;t_++){
        s16x8 vf = ldk(vtc, db, 2*t_ + lh);
        cacc[db] = __builtin_amdgcn_mfma_f32_32x32x16_bf16(pa[t_], vf, cacc[db], 0,0,0);
      }
    }
    __builtin_amdgcn_s_setprio(0);
  };

  ASTAGE(0, kbase);
  for (int ti=0; ti<16; ti++){
    int cur = ti & 1;
    if (ti+1 < 16){
      ASTAGE(cur^1, kbase + (ti+1)*64);
      asm volatile("s_waitcnt vmcnt(4)" ::: "memory");   // retire tile-ti's 4 loads
    } else {
      asm volatile("s_waitcnt vmcnt(0)" ::: "memory");
    }
    __builtin_amdgcn_s_barrier();       // all waves' tile-ti loads now in LDS
    asm volatile("" ::: "memory");
    tile_compute(kt[kh][cur], vt[kh][cur]);
    asm volatile("" ::: "memory");
    __builtin_amdgcn_s_barrier();       // reads of tile ti complete before overwrite
  }
#undef ASTAGE
  // ---- in-LDS split-K combine (kt/vt space is free after the final barrier) ----
  // kh=1 waves publish unnormalized O (f32) + l; kh=0 waves sum, normalize, write ctx.
  float* ob = (float*)kt;           // 4 subtiles x 32q x 64d f32 = 32KB (fits kt exactly)
  float* lf = (float*)vt;           // 128 f32
  if (kh == 1){
#pragma unroll
    for (int db=0;db<2;db++)
#pragma unroll
      for (int reg=0;reg<16;reg++){
        int ql = (reg&3) + 8*(reg>>2) + 4*lh;
        ob[wq*2048 + ql*64 + db*32 + l31] = cacc[db][reg];
      }
    if (lh == 0) lf[wq*32 + l31] = l_;
  }
  __syncthreads();
  if (kh == 0){
    float ltot = l_ + lf[wq*32 + l31];
#pragma unroll
    for (int db=0;db<2;db++)
#pragma unroll
      for (int reg=0;reg<16;reg++){
        int ql = (reg&3) + 8*(reg>>2) + 4*lh;
        cacc[db][reg] += ob[wq*2048 + ql*64 + db*32 + l31];
      }
    size_t pb = (size_t)(b*SS) + q0 + wq*32;
    size_t co = (size_t)h*DKK + l31;
#pragma unroll
    for (int reg=0;reg<16;reg++){
      int qrow = (reg&3) + 8*(reg>>2) + 4*lh;
      float linv = 1.f/__shfl(ltot, qrow);
      ctx[(pb + qrow)*DD + co]      = f2bf(cacc[0][reg]*linv);
      ctx[(pb + qrow)*DD + co + 32] = f2bf(cacc[1][reg]*linv);
    }
  }
}

extern "C" void kernel_launch(void* const* d_in, const int* in_sizes, int n_in,
                              void* d_out, int out_size, void* d_ws, size_t ws_size,
                              hipStream_t stream){
  const float* x   = (const float*)d_in[0];
  const float* Wq  = (const float*)d_in[1];
  const float* Wk  = (const float*)d_in[2];
  const float* Wv  = (const float*)d_in[3];
  const float* Wo  = (const float*)d_in[4];
  const float* bo  = (const float*)d_in[5];
  const float* g1  = (const float*)d_in[6];
  const float* b1  = (const float*)d_in[7];
  const float* g2  = (const float*)d_in[8];
  const float* b2  = (const float*)d_in[9];
  const float* W1  = (const float*)d_in[10];
  const float* bf1 = (const float*)d_in[11];
  const float* W2  = (const float*)d_in[12];
  const float* bf2 = (const float*)d_in[13];
  float* out = (float*)d_out;

  char* p = (char*)d_ws;
  u16* wtq = (u16*)p;                p += (size_t)512*512*2;
  u16* wtk = (u16*)p;                p += (size_t)512*512*2;
  u16* wtv = (u16*)p;                p += (size_t)512*512*2;
  u16* wto = (u16*)p;                p += (size_t)512*512*2;
  u16* wt1 = (u16*)p;                p += (size_t)2048*512*2;
  u16* wt2 = (u16*)p;                p += (size_t)512*2048*2;
  u16* xn1 = (u16*)p;                p += (size_t)8192*512*2;  // reused: ctx, xn2
  u16* Qb  = (u16*)p;                p += (size_t)8192*512*2;  // hb overlay starts here (32MB)
  u16* Kb  = (u16*)p;                p += (size_t)8192*512*2;
  u16* Vtb = (u16*)p;                p += (size_t)8192*512*2;  // V written transposed by QKV GEMM
  /* hb spacer */                    p += (size_t)8192*512*2;  // 4th 8MB of the hb overlay --
                                                               // keeps FFN1's 32MB write off x1b
  u16* x1b = (u16*)p;                p += (size_t)8192*512*2;  // bf16 residual stream
  u16* hb  = Qb;                     // 8192x2048 bf16 = 32MB overlay: Qb+Kb+Vtb+spacer

  dim3 blk(256);
  // fused prep: weight transposes (768 blocks) + LN1 (2048 blocks), one dispatch
  prep_k<<<dim3(2816), blk, 0, stream>>>(Wq, Wk, Wv, Wo, W1, W2,
                                         wtq, wtk, wtv, wto, wt1, wt2,
                                         x, g1, b1, xn1);
  // Q,K,V = xn1 @ W{q,k,v}; z==0 Q (*QSCALE), z==1 K, z==2 V -> Vt (transposed epilogue)
  gemm_bt<0,128,8><<<dim3(4,64,3), dim3(512), 0, stream>>>(xn1, wtq, Qb, nullptr, Vtb,
                                                   8192,512,512, (long)512*512, (long)8192*512);
  // attention (in-block split-K) -> normalized ctx (reuses xn1)
  attn_k<<<dim3(16,8,4), dim3(512), 0, stream>>>(Qb, Kb, Vtb, xn1);
  // x1 = x + ctx @ Wo + bo   (bf16 out; res = fp32 x)
  gemm_bt<1,64,8><<<dim3(4,128,1), dim3(512), 0, stream>>>(xn1, wto, x1b, bo, x, 8192,512,512, 0,0);
  // LN2: bf16 x1 -> bf16 xn2 (reuses xn1)
  lnb_k<<<dim3(2048), blk, 0, stream>>>(x1b, g2, b2, xn1);
  // h = gelu(xn2 @ W1 + bf1)  (bf16 out)
  gemm_bt<2,128,8><<<dim3(16,64,1), dim3(512), 0, stream>>>(xn1, wt1, hb, bf1, nullptr, 8192,2048,512, 0,0);
  // out = x1 + h @ W2 + bf2  (fp32 out; res = bf16 x1)
  gemm_bt<3,64,8><<<dim3(4,128,1), dim3(512), 0, stream>>>(hb, wt2, out, bf2, x1b, 8192,512,2048, 0,0);
}